// Round 4
// baseline (392.927 us; speedup 1.0000x reference)
//
#include <hip/hip_runtime.h>
#include <hip/hip_bf16.h>

// ---------------- problem constants ----------------
#define Bn 16
#define Tn 256
#define Fn 128
#define Cn 32
#define Dn 32
#define EPSf 1e-5f
#define SELU_L 1.0507009873554805f
#define SELU_A 1.6732632423543772f

typedef unsigned short u16;
typedef unsigned int u32;
typedef __attribute__((ext_vector_type(8))) short bf16x8;
typedef __attribute__((ext_vector_type(4))) float f32x4;

struct Ptrs { const void* p[39]; };

// ---------------- param offsets (floats, in ws) ----------------
#define P_C1W 0          // 1024
#define P_C1B 1024       // 32
#define P_MW  1056       // 32  (= c2w*bnA*selu_lambda)
#define P_MK  1088       // 1
#define P_FC  1089       // gat block, 3264 floats
#define P_TCG (1089+3264)
// gat block internal
#define G_APW 0
#define G_APB 1024
#define G_AW  1056
#define G_PWW 1088
#define G_PWB 2112
#define G_POW 2144
#define G_POB 3168
#define G_GS  3200
#define G_GB  3232
#define GAT_SZ 3264
#define P_PFW (P_TCG+GAT_SZ)   // 32
#define P_PFB (P_PFW+32)       // 1
#define P_PTW (P_PFB+1)        // 32
#define P_PTB (P_PTW+32)       // 1
#define P_W1  (P_PTB+1)        // 1024
#define P_W2  (P_W1+1024)      // 1024
#define P_FCW (P_W2+1024)      // 128
#define P_FCB (P_FCW+128)      // 2
#define P_FLAG 10000           // 1.0 if inputs are bf16, 0.0 if fp32

// ---------------- ws layout (floats) ----------------
#define WS_M     10240                    // 524288  (m then M0; DEAD after k3 -> STC overlays)
#define WS_FCATT (WS_M+524288)            // 65536   (B,128,32)
#define WS_TCATT (WS_FCATT+65536)         // 131072  (B,256,32)
#define WS_FCGAT (WS_TCATT+131072)        // 65536
#define WS_TCGAT (WS_FCGAT+65536)         // 131072
#define WS_XF    (WS_TCGAT+131072)        // 32768   (B,64,32)   SFC overlays XF..XFF until k5
#define WS_XT    (WS_XF+32768)            // 65536   (B,128,32)
#define WS_XFF   (WS_XT+65536)            // 32768
#define WS_XTF   (WS_XFF+32768)           // 65536
// score matrices (bf16), overlaid on dead regions:
//   STC: 16*256*256 u16 = 2 MB  -> overlays WS_M (M consumed by k3)
//   SFC: 16*128*128 u16 = 512KB -> overlays WS_XF..WS_XFF (written only from k5 on)

// ---------------- helpers ----------------
__device__ __forceinline__ float bf2f(u16 u) {
    union { u32 i; float f; } v; v.i = ((u32)u) << 16; return v.f;
}
__device__ __forceinline__ u16 f2bf(float f) {
    union { float f; u32 u; } v; v.f = f;
    u32 r = (v.u + 0x7fffu + ((v.u >> 16) & 1u)) >> 16;
    return (u16)r;
}
__device__ __forceinline__ void up2(u32 u, float* o) {
    union { u32 i; float f; } a, b;
    a.i = u << 16; b.i = u & 0xffff0000u;
    o[0] = a.f; o[1] = b.f;
}
__device__ __forceinline__ float tanh_fast(float x) {
    float e = __expf(2.f * x);
    return 1.f - 2.f / (e + 1.f);
}
__device__ __forceinline__ float ldp(const void* p, int i, int isb) {
    return isb ? bf2f(((const u16*)p)[i]) : ((const float*)p)[i];
}

// ---------------- K0: detect dtype + convert/fold params (parallel, 4 blocks) ----------------
__global__ __launch_bounds__(256) void k0_setup(Ptrs in, float* __restrict__ P) {
    __shared__ int sflag;
    int tid = threadIdx.x;
    int blk = blockIdx.x;
    if (tid < 64) {
        const u16* xu = (const u16*)in.p[0];
        int bad = 0;
        #pragma unroll
        for (int q = 0; q < 4; q++) {
            float f = bf2f(xu[tid * 4 + q]);
            float a = fabsf(f);
            if (!(a < 64.f) && !(a == 0.f)) bad++;
        }
        #pragma unroll
        for (int off = 32; off >= 1; off >>= 1) bad += __shfl_xor(bad, off, 64);
        if (tid == 0) sflag = (bad <= 8) ? 1 : 0;
    }
    __syncthreads();
    const int isb = sflag;

    if (blk == 0) {
        if (tid == 0) P[P_FLAG] = (float)isb;
        for (int i = tid; i < 1024; i += 256) P[P_C1W + i] = ldp(in.p[1], i, isb);
        if (tid < 32) {
            float A = ldp(in.p[3], tid, isb) * rsqrtf(ldp(in.p[6], tid, isb) + EPSf);
            float w = ldp(in.p[7], tid, isb);
            P[P_C1B + tid] = ldp(in.p[2], tid, isb);
            P[P_MW + tid] = w * A * SELU_L;
            float Bc = ldp(in.p[4], tid, isb) - ldp(in.p[5], tid, isb) * A;
            float term = w * Bc;
            #pragma unroll
            for (int off = 16; off >= 1; off >>= 1) term += __shfl_xor(term, off, 64);
            if (tid == 0) P[P_MK] = term + ldp(in.p[8], 0, isb);
        }
        if (tid >= 64 && tid < 96) {
            int t = tid - 64;
            P[P_PFW + t] = ldp(in.p[31], t, isb);
            P[P_PTW + t] = ldp(in.p[33], t, isb);
        }
        if (tid == 96) { P[P_PFB] = ldp(in.p[32], 0, isb); P[P_PTB] = ldp(in.p[34], 0, isb); }
        if (tid == 97) P[P_FCB]     = ldp(in.p[38], 0, isb);
        if (tid == 98) P[P_FCB + 1] = ldp(in.p[38], 1, isb);
        if (tid >= 128) P[P_FCW + (tid - 128)] = ldp(in.p[37], tid - 128, isb);
    } else if (blk <= 2) {
        int g = blk - 1;
        int ib = g ? 20 : 9;
        float* G = P + (g ? P_TCG : P_FC);
        for (int i = tid; i < 1024; i += 256) {
            G[G_APW + i] = ldp(in.p[ib + 0], i, isb);
            G[G_PWW + i] = ldp(in.p[ib + 3], i, isb);
            G[G_POW + i] = ldp(in.p[ib + 5], i, isb);
        }
        if (tid < 32) {
            G[G_APB + tid] = ldp(in.p[ib + 1], tid, isb);
            G[G_AW  + tid] = ldp(in.p[ib + 2], tid, isb);
            G[G_PWB + tid] = ldp(in.p[ib + 4], tid, isb);
            G[G_POB + tid] = ldp(in.p[ib + 6], tid, isb);
            float gs = ldp(in.p[ib + 7], tid, isb) * rsqrtf(ldp(in.p[ib + 10], tid, isb) + EPSf);
            G[G_GS + tid] = gs;
            G[G_GB + tid] = ldp(in.p[ib + 8], tid, isb) - ldp(in.p[ib + 9], tid, isb) * gs;
        }
    } else {
        for (int i = tid; i < 1024; i += 256) {
            P[P_W1 + i] = ldp(in.p[35], i, isb);
            P[P_W2 + i] = ldp(in.p[36], i, isb);
        }
    }
}

// ---------------- K1: conv1 + SELU + BN + conv2 -> m (MFMA on bf16 path) ----------------
// rows = B*T*F = 524288. Block: 4 waves x 8 steps x 16 rows = 512 rows. Grid = 1024.
__global__ __launch_bounds__(256) void k1_conv_m(const void* __restrict__ xin,
                                                 const float* __restrict__ P,
                                                 float* __restrict__ M) {
    const int isb = __builtin_amdgcn_readfirstlane((int)P[P_FLAG]);
    int tid = threadIdx.x;
    if (isb) {
        int w = tid >> 6, lane = tid & 63;
        int n = lane & 15, g = lane >> 4, kc = g * 8;
        // B fragments: c1w[o][c], o = n / n+16, k-chunk kc..kc+7 (bit-exact: inputs are bf16)
        bf16x8 b0, b1;
        #pragma unroll
        for (int e = 0; e < 8; e++) {
            b0[e] = (short)f2bf(P[P_C1W + n * 32 + kc + e]);
            b1[e] = (short)f2bf(P[P_C1W + (n + 16) * 32 + kc + e]);
        }
        float cb0 = P[P_C1B + n], cb1 = P[P_C1B + n + 16];
        float mw0 = P[P_MW + n],  mw1 = P[P_MW + n + 16];
        float mk = P[P_MK];
        int rowblk = blockIdx.x * 512 + w * 128;
        for (int s = 0; s < 8; s++) {
            int r0 = rowblk + s * 16;
            const u16* xp = (const u16*)xin + (size_t)r0 * 32;
            bf16x8 a = *(const bf16x8*)(xp + (size_t)(lane & 15) * 32 + kc);
            f32x4 c0 = {0.f, 0.f, 0.f, 0.f}, c1 = {0.f, 0.f, 0.f, 0.f};
            c0 = __builtin_amdgcn_mfma_f32_16x16x32_bf16(a, b0, c0, 0, 0, 0);
            c1 = __builtin_amdgcn_mfma_f32_16x16x32_bf16(a, b1, c1, 0, 0, 0);
            float acc[4];
            #pragma unroll
            for (int r = 0; r < 4; r++) {
                float z0 = c0[r] + cb0, z1 = c1[r] + cb1;
                float s0 = (z0 > 0.f) ? z0 : SELU_A * (__expf(z0) - 1.f);
                float s1 = (z1 > 0.f) ? z1 : SELU_A * (__expf(z1) - 1.f);
                acc[r] = fmaf(mw0, s0, mw1 * s1);
            }
            #pragma unroll
            for (int off = 1; off < 16; off <<= 1) {
                #pragma unroll
                for (int r = 0; r < 4; r++) acc[r] += __shfl_xor(acc[r], off, 64);
            }
            if (n == 0) {
                float4 o4 = make_float4(acc[0] + mk, acc[1] + mk, acc[2] + mk, acc[3] + mk);
                *(float4*)(M + (size_t)r0 + g * 4) = o4;
            }
        }
    } else {
        // fp32 fallback: scalar path, 2 rows per thread
        for (int rr = 0; rr < 2; rr++) {
            int idx = blockIdx.x * 512 + rr * 256 + tid;
            float xv[32];
            const float4* xf4 = reinterpret_cast<const float4*>((const float*)xin + (size_t)idx * 32);
            #pragma unroll
            for (int q = 0; q < 8; q++) {
                float4 v = xf4[q];
                xv[q * 4 + 0] = v.x; xv[q * 4 + 1] = v.y;
                xv[q * 4 + 2] = v.z; xv[q * 4 + 3] = v.w;
            }
            float acc = P[P_MK];
            #pragma unroll
            for (int o = 0; o < 32; o++) {
                float z = P[P_C1B + o];
                #pragma unroll
                for (int c = 0; c < 32; c++) z = fmaf(P[P_C1W + o * 32 + c], xv[c], z);
                float br = (z > 0.f) ? z : SELU_A * (__expf(z) - 1.f);
                acc = fmaf(P[P_MW + o], br, acc);
            }
            M[idx] = acc;
        }
    }
}

// ---------------- K2: softmax over T + zero FCatt (128 blocks) ----------------
__global__ __launch_bounds__(256) void k2_softmax(float* __restrict__ M,
                                                  float* __restrict__ FCzero) {
    __shared__ float r[256];
    int b = blockIdx.x >> 3, fg = blockIdx.x & 7;
    int tid = threadIdx.x;
    int fl = tid & 15, ts = tid >> 4;
    float* col = M + (size_t)b * (Tn * Fn) + fg * 16 + fl;
    float v[16];
    float mx = -1e30f;
    #pragma unroll
    for (int k = 0; k < 16; k++) { v[k] = col[(ts * 16 + k) * Fn]; mx = fmaxf(mx, v[k]); }
    r[tid] = mx; __syncthreads();
    for (int s = 128; s >= 16; s >>= 1) { if (tid < s) r[tid] = fmaxf(r[tid], r[tid + s]); __syncthreads(); }
    mx = r[fl];
    __syncthreads();
    float sm = 0.f;
    #pragma unroll
    for (int k = 0; k < 16; k++) { v[k] = __expf(v[k] - mx); sm += v[k]; }
    r[tid] = sm; __syncthreads();
    for (int s = 128; s >= 16; s >>= 1) { if (tid < s) r[tid] += r[tid + s]; __syncthreads(); }
    float inv = 1.f / r[fl];
    #pragma unroll
    for (int k = 0; k < 16; k++) col[(ts * 16 + k) * Fn] = v[k] * inv;
    int gid = blockIdx.x * 256 + tid;
    for (int i = gid; i < Bn * Fn * Cn; i += 128 * 256) FCzero[i] = 0.f;
}

// ---------------- K3: FCatt (register partials, few atomics) + TCatt ----------------
__global__ __launch_bounds__(256) void k3n(const void* __restrict__ xin,
                                           const float* __restrict__ M,
                                           const float* __restrict__ Pflag,
                                           float* __restrict__ FCatt,
                                           float* __restrict__ TCatt) {
    __shared__ float part[4][8][32];     // [wave][tt][c]
    int bi = blockIdx.x;                 // 512 blocks: b*32 + tg (8 t's each)
    int b = bi >> 5, tg = bi & 31;
    int tid = threadIdx.x;
    int w = tid >> 6, lane = tid & 63;
    const int isb = __builtin_amdgcn_readfirstlane((int)Pflag[P_FLAG]);
    float fa0[8], fa1[8];
    #pragma unroll
    for (int k = 0; k < 8; k++) { fa0[k] = 0.f; fa1[k] = 0.f; }
    int fbase = tid >> 4;
    for (int tt = 0; tt < 8; tt++) {
        int t = tg * 8 + tt;
        const float* Mrow = M + (size_t)b * (Tn * Fn) + (size_t)t * Fn;
        size_t rowoff = ((size_t)b * Tn + t) * (Fn * Cn);
        float ts0 = 0.f, ts1 = 0.f;
        #pragma unroll
        for (int k = 0; k < 8; k++) {
            float x0, x1;
            if (isb) {
                u32 u = *(const u32*)((const u16*)xin + rowoff + tid * 2 + 512 * k);
                float tmp[2]; up2(u, tmp); x0 = tmp[0]; x1 = tmp[1];
            } else {
                float2 v2 = *(const float2*)((const float*)xin + rowoff + tid * 2 + 512 * k);
                x0 = v2.x; x1 = v2.y;
            }
            float m = Mrow[fbase + 16 * k];
            x0 *= m; x1 *= m;
            fa0[k] += x0; fa1[k] += x1;
            ts0 += x0; ts1 += x1;
        }
        ts0 += __shfl_xor(ts0, 16, 64); ts0 += __shfl_xor(ts0, 32, 64);
        ts1 += __shfl_xor(ts1, 16, 64); ts1 += __shfl_xor(ts1, 32, 64);
        if (lane < 16) {
            part[w][tt][lane * 2]     = ts0;
            part[w][tt][lane * 2 + 1] = ts1;
        }
    }
    __syncthreads();
    {
        int tt = tid >> 5, c = tid & 31;
        float s = part[0][tt][c] + part[1][tt][c] + part[2][tt][c] + part[3][tt][c];
        TCatt[((size_t)b * Tn + tg * 8 + tt) * Cn + c] = s;
    }
    #pragma unroll
    for (int k = 0; k < 8; k++) {
        atomicAdd(&FCatt[(size_t)b * 4096 + tid * 2 + 512 * k],     fa0[k]);
        atomicAdd(&FCatt[(size_t)b * 4096 + tid * 2 + 512 * k + 1], fa1[k]);
    }
}

// ---------------- K4a: score tiles via MFMA -> S (bf16) ----------------
// Block = (b, i-group of 16). Waves sweep (i_local, j-step) pairs; one MFMA pair
// computes z[16 j][32 d] for a fixed i; tanh+aw reduce -> 16 scores.
// FC: 128 blocks (16b x 8 groups), TC: 256 blocks (16b x 16 groups).
__global__ __launch_bounds__(256) void k4a_scores(const float* __restrict__ P,
                                                  const float* __restrict__ FCatt,
                                                  const float* __restrict__ TCatt,
                                                  u16* __restrict__ SFC,
                                                  u16* __restrict__ STC) {
    __shared__ float hs[256 * 36];       // padded rows (36 floats = 144B: 16B-aligned, 2-way bank)
    int bi = blockIdx.x;
    int N, b, ib0, jslog; const float* h; u16* S; const float* G;
    if (bi < 128) { N = 128; b = bi >> 3; ib0 = (bi & 7) * 16; jslog = 3;
        h = FCatt + (size_t)b * 4096; S = SFC + (size_t)b * 16384; G = P + P_FC; }
    else { int t = bi - 128; N = 256; b = t >> 4; ib0 = (t & 15) * 16; jslog = 4;
        h = TCatt + (size_t)b * 8192; S = STC + (size_t)b * 65536; G = P + P_TCG; }
    int tid = threadIdx.x;
    int w = tid >> 6, lane = tid & 63;
    int n = lane & 15, g = lane >> 4, kc = g * 8;

    // per-block operand fragments (apw^T as B)
    bf16x8 b0, b1;
    #pragma unroll
    for (int e = 0; e < 8; e++) {
        b0[e] = (short)f2bf(G[G_APW + n * 32 + kc + e]);
        b1[e] = (short)f2bf(G[G_APW + (n + 16) * 32 + kc + e]);
    }
    float aw0 = G[G_AW + n],  aw1 = G[G_AW + n + 16];
    float ab0 = G[G_APB + n], ab1 = G[G_APB + n + 16];

    // stage h (padded)
    const float4* h4 = reinterpret_cast<const float4*>(h);
    for (int el = tid; el < N * 8; el += 256) {
        float4 v = h4[el];
        int row = el >> 3, c = (el & 7) * 4;
        *(float4*)&hs[row * 36 + c] = v;
    }
    __syncthreads();

    int steps = (16 << jslog) >> 2;      // per-wave steps: 32 (FC) / 64 (TC)
    int jmask = (1 << jslog) - 1;
    for (int s = 0; s < steps; s++) {
        int st = s * 4 + w;
        int i = ib0 + (st >> jslog);
        int j0 = (st & jmask) << 4;
        const float* hi = &hs[i * 36 + kc];               // uniform per 16-lane group
        const float* hj = &hs[(j0 + n) * 36 + kc];        // A row n = j0+n
        bf16x8 a;
        #pragma unroll
        for (int e = 0; e < 8; e++) a[e] = (short)f2bf(hi[e] * hj[e]);
        f32x4 c0 = {0.f, 0.f, 0.f, 0.f}, c1 = {0.f, 0.f, 0.f, 0.f};
        c0 = __builtin_amdgcn_mfma_f32_16x16x32_bf16(a, b0, c0, 0, 0, 0);
        c1 = __builtin_amdgcn_mfma_f32_16x16x32_bf16(a, b1, c1, 0, 0, 0);
        float sc[4];
        #pragma unroll
        for (int r = 0; r < 4; r++)
            sc[r] = fmaf(aw0, tanh_fast(c0[r] + ab0), aw1 * tanh_fast(c1[r] + ab1));
        #pragma unroll
        for (int off = 1; off < 16; off <<= 1) {
            #pragma unroll
            for (int r = 0; r < 4; r++) sc[r] += __shfl_xor(sc[r], off, 64);
        }
        if (n == 0) {
            union { u16 q[4]; uint2 v; } pk;
            #pragma unroll
            for (int r = 0; r < 4; r++) pk.q[r] = f2bf(sc[r]);
            *(uint2*)(S + (size_t)i * N + j0 + g * 4) = pk.v;
        }
    }
}

// ---------------- K4b: softmax over j + attsum + output transform ----------------
__global__ __launch_bounds__(256) void k4b_soft(const float* __restrict__ P,
                                                const float* __restrict__ FCatt,
                                                const float* __restrict__ TCatt,
                                                const u16* __restrict__ SFC,
                                                const u16* __restrict__ STC,
                                                float* __restrict__ FCgat,
                                                float* __restrict__ TCgat) {
    __shared__ float hs[256 * 32];
    __shared__ float scb[4][256];
    int bi = blockIdx.x;
    int N, b, rowbase; const float* h; float* out; const float* G; const u16* S;
    if (bi < 128) {
        N = 128; b = bi >> 3; rowbase = (bi & 7) * 16;
        h = FCatt + (size_t)b * 4096; out = FCgat + (size_t)b * 4096; G = P + P_FC;
        S = SFC + (size_t)b * 16384;
    } else {
        int t = bi - 128;
        N = 256; b = t >> 4; rowbase = (t & 15) * 16;
        h = TCatt + (size_t)b * 8192; out = TCgat + (size_t)b * 8192; G = P + P_TCG;
        S = STC + (size_t)b * 65536;
    }
    int tid = threadIdx.x;
    int w = tid >> 6, lane = tid & 63;
    const float4* h4 = reinterpret_cast<const float4*>(h);
    float4* hs4 = reinterpret_cast<float4*>(hs);
    for (int el = tid; el < N * 8; el += 256) hs4[el] = h4[el];
    __syncthreads();

    int c = lane & 31;
    int nq = N >> 6;
    for (int r = 0; r < 4; r++) {
        int row = rowbase + w + 4 * r;
        const u16* Srow = S + (size_t)row * N;
        float v[4];
        float mx = -1e30f;
        for (int q = 0; q < nq; q++) { v[q] = bf2f(Srow[lane + 64 * q]); mx = fmaxf(mx, v[q]); }
        #pragma unroll
        for (int off = 32; off >= 1; off >>= 1) mx = fmaxf(mx, __shfl_xor(mx, off, 64));
        float sum = 0.f;
        for (int q = 0; q < nq; q++) {
            float e = __expf(v[q] - mx);
            scb[w][lane + 64 * q] = e;
            sum += e;
        }
        #pragma unroll
        for (int off = 32; off >= 1; off >>= 1) sum += __shfl_xor(sum, off, 64);
        float inv = 1.f / sum;
        asm volatile("s_waitcnt lgkmcnt(0)" ::: "memory");
        int half = lane >> 5;
        float acc = 0.f;
        for (int j = half; j < N; j += 2) acc = fmaf(scb[w][j], hs[j * 32 + c], acc);
        acc += __shfl_xor(acc, 32, 64);
        acc *= inv;
        int d = c;
        float z = G[G_PWB + d] + G[G_POB + d];
        #pragma unroll
        for (int c2 = 0; c2 < 32; c2++)
            z = fmaf(G[G_PWW + d * 32 + c2], __shfl(acc, c2, 64),
                fmaf(G[G_POW + d * 32 + c2], hs[row * 32 + c2], z));
        z = z * G[G_GS + d] + G[G_GB + d];
        z = SELU_L * ((z > 0.f) ? z : SELU_A * (__expf(z) - 1.f));
        if (lane < 32) out[(size_t)row * 32 + d] = z;
    }
}

// ---------------- K5: top-k pooling (rank-select) ----------------
__global__ __launch_bounds__(256) void k5_pool(const float* __restrict__ P,
                                               const float* __restrict__ FCgat,
                                               const float* __restrict__ TCgat,
                                               float* __restrict__ XF,
                                               float* __restrict__ XT) {
    __shared__ float s[256];
    int bi = blockIdx.x;
    int N, kn, b, pboff; const float* g; float* xp; const float* pw;
    if (bi < 16) { b = bi; N = 128; kn = 64;
        g = FCgat + (size_t)b * 4096; xp = XF + (size_t)b * 2048; pw = P + P_PFW; pboff = P_PFB; }
    else { b = bi - 16; N = 256; kn = 128;
        g = TCgat + (size_t)b * 8192; xp = XT + (size_t)b * 4096; pw = P + P_PTW; pboff = P_PTB; }
    int tid = threadIdx.x;
    float sv = 0.f;
    if (tid < N) {
        float z = P[pboff];
        #pragma unroll
        for (int d = 0; d < 32; d++) z = fmaf(pw[d], g[(size_t)tid * 32 + d], z);
        sv = 1.f / (1.f + __expf(-z));
        s[tid] = sv;
    }
    __syncthreads();
    if (tid < N) {
        int rank = 0;
        for (int l = 0; l < N; l++) {
            float sl = s[l];
            rank += (sl > sv) || (sl == sv && l < tid);
        }
        if (rank < kn) {
            #pragma unroll
            for (int d = 0; d < 32; d++) xp[(size_t)rank * 32 + d] = g[(size_t)tid * 32 + d] * sv;
        }
    }
}

// ---------------- K6: cross fusion (wave per output row) ----------------
__global__ __launch_bounds__(256) void k6_fuse(const float* __restrict__ P,
                                               const float* __restrict__ XF,
                                               const float* __restrict__ XT,
                                               float* __restrict__ XFF,
                                               float* __restrict__ XTF) {
    int wid = blockIdx.x * 4 + (threadIdx.x >> 6);
    int lane = threadIdx.x & 63;
    if (wid < 1024) {
        int b = wid >> 6, i = wid & 63;
        const float* xf  = XF + ((size_t)b * 64 + i) * 32;
        const float* xtb = XT + (size_t)b * 4096;
        const float* w1 = P + P_W1;
        int d = lane & 31;
        float y = 0.f;
        #pragma unroll
        for (int c = 0; c < 32; c++) y = fmaf(w1[d * 32 + c], xf[c], y);
        float xtr0[32], xtr1[32];
        #pragma unroll
        for (int c = 0; c < 32; c++) {
            xtr0[c] = xtb[(size_t)lane * 32 + c];
            xtr1[c] = xtb[(size_t)(lane + 64) * 32 + c];
        }
        float s0 = 0.f, s1 = 0.f;
        #pragma unroll
        for (int c = 0; c < 32; c++) {
            float yc = __shfl(y, c, 64);
            s0 = fmaf(yc, xtr0[c], s0);
            s1 = fmaf(yc, xtr1[c], s1);
        }
        float mx = fmaxf(s0, s1);
        #pragma unroll
        for (int off = 1; off < 64; off <<= 1) mx = fmaxf(mx, __shfl_xor(mx, off, 64));
        float e0 = __expf(s0 - mx), e1 = __expf(s1 - mx);
        float sm = e0 + e1;
        #pragma unroll
        for (int off = 1; off < 64; off <<= 1) sm += __shfl_xor(sm, off, 64);
        float inv = 1.f / sm;
        float a0 = e0 * inv, a1 = e1 * inv;
        float v[32];
        #pragma unroll
        for (int c = 0; c < 32; c++) v[c] = a0 * xtr0[c] + a1 * xtr1[c];
        #pragma unroll
        for (int off = 1; off < 64; off <<= 1) {
            #pragma unroll
            for (int c = 0; c < 32; c++) v[c] += __shfl_xor(v[c], off, 64);
        }
        if (lane == 0) {
            float* o = XFF + ((size_t)b * 64 + i) * 32;
            #pragma unroll
            for (int c = 0; c < 32; c++) o[c] = xf[c] + v[c];
        }
    } else {
        int r = wid - 1024;
        int b = r >> 7, i = r & 127;
        const float* xt  = XT + ((size_t)b * 128 + i) * 32;
        const float* xfb = XF + (size_t)b * 2048;
        const float* w2 = P + P_W2;
        int d = lane & 31;
        float y = 0.f;
        #pragma unroll
        for (int c = 0; c < 32; c++) y = fmaf(w2[d * 32 + c], xt[c], y);
        float xfr[32];
        #pragma unroll
        for (int c = 0; c < 32; c++) xfr[c] = xfb[(size_t)lane * 32 + c];
        float sc0 = 0.f;
        #pragma unroll
        for (int c = 0; c < 32; c++) sc0 = fmaf(__shfl(y, c, 64), xfr[c], sc0);
        float mx = sc0;
        #pragma unroll
        for (int off = 1; off < 64; off <<= 1) mx = fmaxf(mx, __shfl_xor(mx, off, 64));
        float e = __expf(sc0 - mx);
        float sm = e;
        #pragma unroll
        for (int off = 1; off < 64; off <<= 1) sm += __shfl_xor(sm, off, 64);
        float a = e / sm;
        float v[32];
        #pragma unroll
        for (int c = 0; c < 32; c++) v[c] = a * xfr[c];
        #pragma unroll
        for (int off = 1; off < 64; off <<= 1) {
            #pragma unroll
            for (int c = 0; c < 32; c++) v[c] += __shfl_xor(v[c], off, 64);
        }
        if (lane == 0) {
            float* o = XTF + ((size_t)b * 128 + i) * 32;
            #pragma unroll
            for (int c = 0; c < 32; c++) o[c] = xt[c] + v[c];
        }
    }
}

// ---------------- K7: row-max + final FC (dtype-aware output) ----------------
__global__ __launch_bounds__(64) void k7_out(const float* __restrict__ P,
                                             const float* __restrict__ XFF,
                                             const float* __restrict__ XTF,
                                             void* __restrict__ outp) {
    __shared__ float node[64];
    int b = blockIdx.x, tid = threadIdx.x;
    if (tid < 32) {
        float m = -1e30f;
        for (int r = 0; r < 64; r++) m = fmaxf(m, XFF[((size_t)b * 64 + r) * 32 + tid]);
        node[tid] = m;
    } else {
        int c = tid - 32;
        float m = -1e30f;
        for (int r = 0; r < 128; r++) m = fmaxf(m, XTF[((size_t)b * 128 + r) * 32 + c]);
        node[tid] = m;
    }
    __syncthreads();
    if (tid < 2) {
        float z = P[P_FCB + tid];
        #pragma unroll
        for (int k = 0; k < 64; k++) z = fmaf(P[P_FCW + tid * 64 + k], node[k], z);
        int isb = (int)P[P_FLAG];
        if (isb) ((u16*)outp)[b * 2 + tid] = f2bf(z);
        else     ((float*)outp)[b * 2 + tid] = z;
    }
}

// ---------------- launch ----------------
extern "C" void kernel_launch(void* const* d_in, const int* in_sizes, int n_in,
                              void* d_out, int out_size, void* d_ws, size_t ws_size,
                              hipStream_t stream) {
    (void)in_sizes; (void)n_in; (void)out_size; (void)ws_size;
    float* W = (float*)d_ws;
    Ptrs ptrs;
    for (int i = 0; i < 39; i++) ptrs.p[i] = d_in[i];
    const void* x = d_in[0];
    float* P = W;
    u16* STC = (u16*)(W + WS_M);    // overlays M (dead after k3)
    u16* SFC = (u16*)(W + WS_XF);   // overlays XF..XFF (free until k5)

    k0_setup<<<4, 256, 0, stream>>>(ptrs, P);
    k1_conv_m<<<1024, 256, 0, stream>>>(x, P, W + WS_M);
    k2_softmax<<<128, 256, 0, stream>>>(W + WS_M, W + WS_FCATT);
    k3n<<<512, 256, 0, stream>>>(x, W + WS_M, P, W + WS_FCATT, W + WS_TCATT);
    k4a_scores<<<384, 256, 0, stream>>>(P, W + WS_FCATT, W + WS_TCATT, SFC, STC);
    k4b_soft<<<384, 256, 0, stream>>>(P, W + WS_FCATT, W + WS_TCATT, SFC, STC,
                                      W + WS_FCGAT, W + WS_TCGAT);
    k5_pool<<<32, 256, 0, stream>>>(P, W + WS_FCGAT, W + WS_TCGAT, W + WS_XF, W + WS_XT);
    k6_fuse<<<768, 256, 0, stream>>>(P, W + WS_XF, W + WS_XT, W + WS_XFF, W + WS_XTF);
    k7_out<<<16, 64, 0, stream>>>(P, W + WS_XFF, W + WS_XTF, d_out);
}

// Round 5
// 334.744 us; speedup vs baseline: 1.1738x; 1.1738x over previous
//
#include <hip/hip_runtime.h>
#include <hip/hip_bf16.h>

// ---------------- problem constants ----------------
#define Bn 16
#define Tn 256
#define Fn 128
#define Cn 32
#define Dn 32
#define EPSf 1e-5f
#define SELU_L 1.0507009873554805f
#define SELU_A 1.6732632423543772f

typedef unsigned short u16;
typedef unsigned int u32;
typedef __attribute__((ext_vector_type(8))) short bf16x8;
typedef __attribute__((ext_vector_type(4))) float f32x4;

struct Ptrs { const void* p[39]; };

// ---------------- param offsets (floats, in ws) ----------------
#define P_C1W 0          // 1024
#define P_C1B 1024       // 32
#define P_MW  1056       // 32  (= c2w*bnA*selu_lambda)
#define P_MK  1088       // 1
#define P_FC  1089       // gat block, 3264 floats
#define P_TCG (1089+3264)
// gat block internal
#define G_APW 0
#define G_APB 1024
#define G_AW  1056
#define G_PWW 1088
#define G_PWB 2112
#define G_POW 2144
#define G_POB 3168
#define G_GS  3200
#define G_GB  3232
#define GAT_SZ 3264
#define P_PFW (P_TCG+GAT_SZ)   // 32
#define P_PFB (P_PFW+32)       // 1
#define P_PTW (P_PFB+1)        // 32
#define P_PTB (P_PTW+32)       // 1
#define P_W1  (P_PTB+1)        // 1024
#define P_W2  (P_W1+1024)      // 1024
#define P_FCW (P_W2+1024)      // 128
#define P_FCB (P_FCW+128)      // 2
#define P_FLAG 10000           // 1.0 if inputs are bf16, 0.0 if fp32

// ---------------- ws layout (floats) ----------------
#define WS_M     10240                    // 524288  (m then M0; DEAD after k3 -> STC overlays)
#define WS_FCATT (WS_M+524288)            // 65536   (B,128,32)
#define WS_TCATT (WS_FCATT+65536)         // 131072  (B,256,32)
#define WS_FCGAT (WS_TCATT+131072)        // 65536
#define WS_TCGAT (WS_FCGAT+65536)         // 131072
#define WS_XF    (WS_TCGAT+131072)        // 32768   (B,64,32)   SFC overlays XF..XFF until k5
#define WS_XT    (WS_XF+32768)            // 65536   (B,128,32)
#define WS_XFF   (WS_XT+65536)            // 32768
#define WS_XTF   (WS_XFF+32768)           // 65536
// score matrices (bf16), overlaid on dead regions:
//   STC: 16*256*256 u16 = 2 MB  -> overlays WS_M (M consumed by k3)
//   SFC: 16*128*128 u16 = 512KB -> overlays WS_XF..WS_XFF (written only from k5 on)

// ---------------- helpers ----------------
__device__ __forceinline__ float bf2f(u16 u) {
    union { u32 i; float f; } v; v.i = ((u32)u) << 16; return v.f;
}
__device__ __forceinline__ u16 f2bf(float f) {
    union { float f; u32 u; } v; v.f = f;
    u32 r = (v.u + 0x7fffu + ((v.u >> 16) & 1u)) >> 16;
    return (u16)r;
}
__device__ __forceinline__ void up2(u32 u, float* o) {
    union { u32 i; float f; } a, b;
    a.i = u << 16; b.i = u & 0xffff0000u;
    o[0] = a.f; o[1] = b.f;
}
__device__ __forceinline__ float tanh_fast(float x) {
    float e = __expf(2.f * x);
    return 1.f - 2.f / (e + 1.f);
}
__device__ __forceinline__ float ldp(const void* p, int i, int isb) {
    return isb ? bf2f(((const u16*)p)[i]) : ((const float*)p)[i];
}

// ---------------- K0: detect dtype + convert/fold params (parallel, 4 blocks) ----------------
__global__ __launch_bounds__(256) void k0_setup(Ptrs in, float* __restrict__ P) {
    __shared__ int sflag;
    int tid = threadIdx.x;
    int blk = blockIdx.x;
    if (tid < 64) {
        const u16* xu = (const u16*)in.p[0];
        int bad = 0;
        #pragma unroll
        for (int q = 0; q < 4; q++) {
            float f = bf2f(xu[tid * 4 + q]);
            float a = fabsf(f);
            if (!(a < 64.f) && !(a == 0.f)) bad++;
        }
        #pragma unroll
        for (int off = 32; off >= 1; off >>= 1) bad += __shfl_xor(bad, off, 64);
        if (tid == 0) sflag = (bad <= 8) ? 1 : 0;
    }
    __syncthreads();
    const int isb = sflag;

    if (blk == 0) {
        if (tid == 0) P[P_FLAG] = (float)isb;
        for (int i = tid; i < 1024; i += 256) P[P_C1W + i] = ldp(in.p[1], i, isb);
        if (tid < 32) {
            float A = ldp(in.p[3], tid, isb) * rsqrtf(ldp(in.p[6], tid, isb) + EPSf);
            float w = ldp(in.p[7], tid, isb);
            P[P_C1B + tid] = ldp(in.p[2], tid, isb);
            P[P_MW + tid] = w * A * SELU_L;
            float Bc = ldp(in.p[4], tid, isb) - ldp(in.p[5], tid, isb) * A;
            float term = w * Bc;
            #pragma unroll
            for (int off = 16; off >= 1; off >>= 1) term += __shfl_xor(term, off, 64);
            if (tid == 0) P[P_MK] = term + ldp(in.p[8], 0, isb);
        }
        if (tid >= 64 && tid < 96) {
            int t = tid - 64;
            P[P_PFW + t] = ldp(in.p[31], t, isb);
            P[P_PTW + t] = ldp(in.p[33], t, isb);
        }
        if (tid == 96) { P[P_PFB] = ldp(in.p[32], 0, isb); P[P_PTB] = ldp(in.p[34], 0, isb); }
        if (tid == 97) P[P_FCB]     = ldp(in.p[38], 0, isb);
        if (tid == 98) P[P_FCB + 1] = ldp(in.p[38], 1, isb);
        if (tid >= 128) P[P_FCW + (tid - 128)] = ldp(in.p[37], tid - 128, isb);
    } else if (blk <= 2) {
        int g = blk - 1;
        int ib = g ? 20 : 9;
        float* G = P + (g ? P_TCG : P_FC);
        for (int i = tid; i < 1024; i += 256) {
            G[G_APW + i] = ldp(in.p[ib + 0], i, isb);
            G[G_PWW + i] = ldp(in.p[ib + 3], i, isb);
            G[G_POW + i] = ldp(in.p[ib + 5], i, isb);
        }
        if (tid < 32) {
            G[G_APB + tid] = ldp(in.p[ib + 1], tid, isb);
            G[G_AW  + tid] = ldp(in.p[ib + 2], tid, isb);
            G[G_PWB + tid] = ldp(in.p[ib + 4], tid, isb);
            G[G_POB + tid] = ldp(in.p[ib + 6], tid, isb);
            float gs = ldp(in.p[ib + 7], tid, isb) * rsqrtf(ldp(in.p[ib + 10], tid, isb) + EPSf);
            G[G_GS + tid] = gs;
            G[G_GB + tid] = ldp(in.p[ib + 8], tid, isb) - ldp(in.p[ib + 9], tid, isb) * gs;
        }
    } else {
        for (int i = tid; i < 1024; i += 256) {
            P[P_W1 + i] = ldp(in.p[35], i, isb);
            P[P_W2 + i] = ldp(in.p[36], i, isb);
        }
    }
}

// ---------------- K1: conv1 + SELU + BN + conv2 -> m (MFMA, prefetched) ----------------
// rows = B*T*F = 524288. Grid 2048 x 256: wave handles 64 rows = 4 tiles, all 4
// A-tile loads issued up-front (independent, in flight together).
__global__ __launch_bounds__(256) void k1_conv_m(const void* __restrict__ xin,
                                                 const float* __restrict__ P,
                                                 float* __restrict__ M) {
    const int isb = __builtin_amdgcn_readfirstlane((int)P[P_FLAG]);
    int tid = threadIdx.x;
    if (isb) {
        int w = tid >> 6, lane = tid & 63;
        int n = lane & 15, g = lane >> 4, kc = g * 8;
        bf16x8 b0, b1;
        #pragma unroll
        for (int e = 0; e < 8; e++) {
            b0[e] = (short)f2bf(P[P_C1W + n * 32 + kc + e]);
            b1[e] = (short)f2bf(P[P_C1W + (n + 16) * 32 + kc + e]);
        }
        float cb0 = P[P_C1B + n], cb1 = P[P_C1B + n + 16];
        float mw0 = P[P_MW + n],  mw1 = P[P_MW + n + 16];
        float mk = P[P_MK];
        int rowblk = blockIdx.x * 256 + w * 64;
        const u16* xp = (const u16*)xin + (size_t)rowblk * 32;
        bf16x8 a[4];
        #pragma unroll
        for (int s = 0; s < 4; s++)
            a[s] = *(const bf16x8*)(xp + ((size_t)s * 16 + n) * 32 + kc);
        #pragma unroll
        for (int s = 0; s < 4; s++) {
            f32x4 c0 = {0.f, 0.f, 0.f, 0.f}, c1 = {0.f, 0.f, 0.f, 0.f};
            c0 = __builtin_amdgcn_mfma_f32_16x16x32_bf16(a[s], b0, c0, 0, 0, 0);
            c1 = __builtin_amdgcn_mfma_f32_16x16x32_bf16(a[s], b1, c1, 0, 0, 0);
            float acc[4];
            #pragma unroll
            for (int r = 0; r < 4; r++) {
                float z0 = c0[r] + cb0, z1 = c1[r] + cb1;
                float s0 = (z0 > 0.f) ? z0 : SELU_A * (__expf(z0) - 1.f);
                float s1 = (z1 > 0.f) ? z1 : SELU_A * (__expf(z1) - 1.f);
                acc[r] = fmaf(mw0, s0, mw1 * s1);
            }
            #pragma unroll
            for (int off = 1; off < 16; off <<= 1) {
                #pragma unroll
                for (int r = 0; r < 4; r++) acc[r] += __shfl_xor(acc[r], off, 64);
            }
            if (n == 0) {
                float4 o4 = make_float4(acc[0] + mk, acc[1] + mk, acc[2] + mk, acc[3] + mk);
                *(float4*)(M + (size_t)rowblk + s * 16 + g * 4) = o4;
            }
        }
    } else {
        // fp32 fallback: 1 row per thread
        int idx = blockIdx.x * 256 + tid;
        float xv[32];
        const float4* xf4 = reinterpret_cast<const float4*>((const float*)xin + (size_t)idx * 32);
        #pragma unroll
        for (int q = 0; q < 8; q++) {
            float4 v = xf4[q];
            xv[q * 4 + 0] = v.x; xv[q * 4 + 1] = v.y;
            xv[q * 4 + 2] = v.z; xv[q * 4 + 3] = v.w;
        }
        float acc = P[P_MK];
        #pragma unroll
        for (int o = 0; o < 32; o++) {
            float z = P[P_C1B + o];
            #pragma unroll
            for (int c = 0; c < 32; c++) z = fmaf(P[P_C1W + o * 32 + c], xv[c], z);
            float br = (z > 0.f) ? z : SELU_A * (__expf(z) - 1.f);
            acc = fmaf(P[P_MW + o], br, acc);
        }
        M[idx] = acc;
    }
}

// ---------------- K2: softmax over T + zero FCatt (128 blocks) ----------------
__global__ __launch_bounds__(256) void k2_softmax(float* __restrict__ M,
                                                  float* __restrict__ FCzero) {
    __shared__ float r[256];
    int b = blockIdx.x >> 3, fg = blockIdx.x & 7;
    int tid = threadIdx.x;
    int fl = tid & 15, ts = tid >> 4;
    float* col = M + (size_t)b * (Tn * Fn) + fg * 16 + fl;
    float v[16];
    float mx = -1e30f;
    #pragma unroll
    for (int k = 0; k < 16; k++) { v[k] = col[(ts * 16 + k) * Fn]; mx = fmaxf(mx, v[k]); }
    r[tid] = mx; __syncthreads();
    for (int s = 128; s >= 16; s >>= 1) { if (tid < s) r[tid] = fmaxf(r[tid], r[tid + s]); __syncthreads(); }
    mx = r[fl];
    __syncthreads();
    float sm = 0.f;
    #pragma unroll
    for (int k = 0; k < 16; k++) { v[k] = __expf(v[k] - mx); sm += v[k]; }
    r[tid] = sm; __syncthreads();
    for (int s = 128; s >= 16; s >>= 1) { if (tid < s) r[tid] += r[tid + s]; __syncthreads(); }
    float inv = 1.f / r[fl];
    #pragma unroll
    for (int k = 0; k < 16; k++) col[(ts * 16 + k) * Fn] = v[k] * inv;
    int gid = blockIdx.x * 256 + tid;
    for (int i = gid; i < Bn * Fn * Cn; i += 128 * 256) FCzero[i] = 0.f;
}

// ---------------- K3: FCatt (register partials, few atomics) + TCatt ----------------
__global__ __launch_bounds__(256) void k3n(const void* __restrict__ xin,
                                           const float* __restrict__ M,
                                           const float* __restrict__ Pflag,
                                           float* __restrict__ FCatt,
                                           float* __restrict__ TCatt) {
    __shared__ float part[4][8][32];     // [wave][tt][c]
    int bi = blockIdx.x;                 // 512 blocks: b*32 + tg (8 t's each)
    int b = bi >> 5, tg = bi & 31;
    int tid = threadIdx.x;
    int w = tid >> 6, lane = tid & 63;
    const int isb = __builtin_amdgcn_readfirstlane((int)Pflag[P_FLAG]);
    float fa0[8], fa1[8];
    #pragma unroll
    for (int k = 0; k < 8; k++) { fa0[k] = 0.f; fa1[k] = 0.f; }
    int fbase = tid >> 4;
    for (int tt = 0; tt < 8; tt++) {
        int t = tg * 8 + tt;
        const float* Mrow = M + (size_t)b * (Tn * Fn) + (size_t)t * Fn;
        size_t rowoff = ((size_t)b * Tn + t) * (Fn * Cn);
        float ts0 = 0.f, ts1 = 0.f;
        #pragma unroll
        for (int k = 0; k < 8; k++) {
            float x0, x1;
            if (isb) {
                u32 u = *(const u32*)((const u16*)xin + rowoff + tid * 2 + 512 * k);
                float tmp[2]; up2(u, tmp); x0 = tmp[0]; x1 = tmp[1];
            } else {
                float2 v2 = *(const float2*)((const float*)xin + rowoff + tid * 2 + 512 * k);
                x0 = v2.x; x1 = v2.y;
            }
            float m = Mrow[fbase + 16 * k];
            x0 *= m; x1 *= m;
            fa0[k] += x0; fa1[k] += x1;
            ts0 += x0; ts1 += x1;
        }
        ts0 += __shfl_xor(ts0, 16, 64); ts0 += __shfl_xor(ts0, 32, 64);
        ts1 += __shfl_xor(ts1, 16, 64); ts1 += __shfl_xor(ts1, 32, 64);
        if (lane < 16) {
            part[w][tt][lane * 2]     = ts0;
            part[w][tt][lane * 2 + 1] = ts1;
        }
    }
    __syncthreads();
    {
        int tt = tid >> 5, c = tid & 31;
        float s = part[0][tt][c] + part[1][tt][c] + part[2][tt][c] + part[3][tt][c];
        TCatt[((size_t)b * Tn + tg * 8 + tt) * Cn + c] = s;
    }
    #pragma unroll
    for (int k = 0; k < 8; k++) {
        atomicAdd(&FCatt[(size_t)b * 4096 + tid * 2 + 512 * k],     fa0[k]);
        atomicAdd(&FCatt[(size_t)b * 4096 + tid * 2 + 512 * k + 1], fa1[k]);
    }
}

// ---------------- K4a: score tiles via MFMA, LDS-free (L2-direct) ----------------
// One wave per (b, i): loop over j-tiles of 16; A = pairwise products built from
// global h (L2-resident, 16-64KB per b), B = apw^T fragments. No LDS, no conflicts.
// FC: 2048 waves, TC: 4096 waves -> 1536 blocks of 4 waves.
__global__ __launch_bounds__(256) void k4a_scores(const float* __restrict__ P,
                                                  const float* __restrict__ FCatt,
                                                  const float* __restrict__ TCatt,
                                                  u16* __restrict__ SFC,
                                                  u16* __restrict__ STC) {
    int bi = blockIdx.x;
    int tid = threadIdx.x;
    int w = tid >> 6, lane = tid & 63;
    int n = lane & 15, g = lane >> 4, kc = g * 8;
    int N, nt, b, i; const float* h; u16* S; const float* G;
    if (bi < 512) { N = 128; nt = 8; b = bi >> 5; i = (bi & 31) * 4 + w;
        h = FCatt + (size_t)b * 4096; S = SFC + (size_t)b * 16384; G = P + P_FC; }
    else { int t = bi - 512; N = 256; nt = 16; b = t >> 6; i = (t & 63) * 4 + w;
        h = TCatt + (size_t)b * 8192; S = STC + (size_t)b * 65536; G = P + P_TCG; }

    // B fragments (apw^T) + epilogue params
    bf16x8 b0, b1;
    #pragma unroll
    for (int e = 0; e < 8; e++) {
        b0[e] = (short)f2bf(G[G_APW + n * 32 + kc + e]);
        b1[e] = (short)f2bf(G[G_APW + (n + 16) * 32 + kc + e]);
    }
    float aw0 = G[G_AW + n],  aw1 = G[G_AW + n + 16];
    float ab0 = G[G_APB + n], ab1 = G[G_APB + n + 16];

    // h_i fragment (uniform within 16-lane group)
    float hi[8];
    {
        const float4* hip = (const float4*)(h + (size_t)i * 32 + kc);
        float4 v0 = hip[0], v1 = hip[1];
        hi[0] = v0.x; hi[1] = v0.y; hi[2] = v0.z; hi[3] = v0.w;
        hi[4] = v1.x; hi[5] = v1.y; hi[6] = v1.z; hi[7] = v1.w;
    }

    for (int jt = 0; jt < nt; jt++) {
        const float4* hjp = (const float4*)(h + ((size_t)jt * 16 + n) * 32 + kc);
        float4 v0 = hjp[0], v1 = hjp[1];
        float hj[8];
        hj[0] = v0.x; hj[1] = v0.y; hj[2] = v0.z; hj[3] = v0.w;
        hj[4] = v1.x; hj[5] = v1.y; hj[6] = v1.z; hj[7] = v1.w;
        bf16x8 a;
        #pragma unroll
        for (int e = 0; e < 8; e++) a[e] = (short)f2bf(hi[e] * hj[e]);
        f32x4 c0 = {0.f, 0.f, 0.f, 0.f}, c1 = {0.f, 0.f, 0.f, 0.f};
        c0 = __builtin_amdgcn_mfma_f32_16x16x32_bf16(a, b0, c0, 0, 0, 0);
        c1 = __builtin_amdgcn_mfma_f32_16x16x32_bf16(a, b1, c1, 0, 0, 0);
        float sc[4];
        #pragma unroll
        for (int r = 0; r < 4; r++)
            sc[r] = fmaf(aw0, tanh_fast(c0[r] + ab0), aw1 * tanh_fast(c1[r] + ab1));
        #pragma unroll
        for (int off = 1; off < 16; off <<= 1) {
            #pragma unroll
            for (int r = 0; r < 4; r++) sc[r] += __shfl_xor(sc[r], off, 64);
        }
        if (n == 0) {
            union { u16 q[4]; uint2 v; } pk;
            #pragma unroll
            for (int r = 0; r < 4; r++) pk.q[r] = f2bf(sc[r]);
            *(uint2*)(S + (size_t)i * N + jt * 16 + g * 4) = pk.v;
        }
    }
}

// ---------------- K4b: softmax over j + attsum + output transform ----------------
__global__ __launch_bounds__(256) void k4b_soft(const float* __restrict__ P,
                                                const float* __restrict__ FCatt,
                                                const float* __restrict__ TCatt,
                                                const u16* __restrict__ SFC,
                                                const u16* __restrict__ STC,
                                                float* __restrict__ FCgat,
                                                float* __restrict__ TCgat) {
    __shared__ float hs[256 * 32];
    __shared__ float scb[4][256];
    int bi = blockIdx.x;
    int N, b, rowbase; const float* h; float* out; const float* G; const u16* S;
    if (bi < 128) {
        N = 128; b = bi >> 3; rowbase = (bi & 7) * 16;
        h = FCatt + (size_t)b * 4096; out = FCgat + (size_t)b * 4096; G = P + P_FC;
        S = SFC + (size_t)b * 16384;
    } else {
        int t = bi - 128;
        N = 256; b = t >> 4; rowbase = (t & 15) * 16;
        h = TCatt + (size_t)b * 8192; out = TCgat + (size_t)b * 8192; G = P + P_TCG;
        S = STC + (size_t)b * 65536;
    }
    int tid = threadIdx.x;
    int w = tid >> 6, lane = tid & 63;
    const float4* h4 = reinterpret_cast<const float4*>(h);
    float4* hs4 = reinterpret_cast<float4*>(hs);
    for (int el = tid; el < N * 8; el += 256) hs4[el] = h4[el];
    __syncthreads();

    int c = lane & 31;
    int nq = N >> 6;
    for (int r = 0; r < 4; r++) {
        int row = rowbase + w + 4 * r;
        const u16* Srow = S + (size_t)row * N;
        float v[4];
        float mx = -1e30f;
        for (int q = 0; q < nq; q++) { v[q] = bf2f(Srow[lane + 64 * q]); mx = fmaxf(mx, v[q]); }
        #pragma unroll
        for (int off = 32; off >= 1; off >>= 1) mx = fmaxf(mx, __shfl_xor(mx, off, 64));
        float sum = 0.f;
        for (int q = 0; q < nq; q++) {
            float e = __expf(v[q] - mx);
            scb[w][lane + 64 * q] = e;
            sum += e;
        }
        #pragma unroll
        for (int off = 32; off >= 1; off >>= 1) sum += __shfl_xor(sum, off, 64);
        float inv = 1.f / sum;
        asm volatile("s_waitcnt lgkmcnt(0)" ::: "memory");
        int half = lane >> 5;
        float acc = 0.f;
        for (int j = half; j < N; j += 2) acc = fmaf(scb[w][j], hs[j * 32 + c], acc);
        acc += __shfl_xor(acc, 32, 64);
        acc *= inv;
        int d = c;
        float z = G[G_PWB + d] + G[G_POB + d];
        #pragma unroll
        for (int c2 = 0; c2 < 32; c2++)
            z = fmaf(G[G_PWW + d * 32 + c2], __shfl(acc, c2, 64),
                fmaf(G[G_POW + d * 32 + c2], hs[row * 32 + c2], z));
        z = z * G[G_GS + d] + G[G_GB + d];
        z = SELU_L * ((z > 0.f) ? z : SELU_A * (__expf(z) - 1.f));
        if (lane < 32) out[(size_t)row * 32 + d] = z;
    }
}

// ---------------- K5: top-k pooling (rank-select) ----------------
__global__ __launch_bounds__(256) void k5_pool(const float* __restrict__ P,
                                               const float* __restrict__ FCgat,
                                               const float* __restrict__ TCgat,
                                               float* __restrict__ XF,
                                               float* __restrict__ XT) {
    __shared__ float s[256];
    int bi = blockIdx.x;
    int N, kn, b, pboff; const float* g; float* xp; const float* pw;
    if (bi < 16) { b = bi; N = 128; kn = 64;
        g = FCgat + (size_t)b * 4096; xp = XF + (size_t)b * 2048; pw = P + P_PFW; pboff = P_PFB; }
    else { b = bi - 16; N = 256; kn = 128;
        g = TCgat + (size_t)b * 8192; xp = XT + (size_t)b * 4096; pw = P + P_PTW; pboff = P_PTB; }
    int tid = threadIdx.x;
    float sv = 0.f;
    if (tid < N) {
        float z = P[pboff];
        #pragma unroll
        for (int d = 0; d < 32; d++) z = fmaf(pw[d], g[(size_t)tid * 32 + d], z);
        sv = 1.f / (1.f + __expf(-z));
        s[tid] = sv;
    }
    __syncthreads();
    if (tid < N) {
        int rank = 0;
        for (int l = 0; l < N; l++) {
            float sl = s[l];
            rank += (sl > sv) || (sl == sv && l < tid);
        }
        if (rank < kn) {
            #pragma unroll
            for (int d = 0; d < 32; d++) xp[(size_t)rank * 32 + d] = g[(size_t)tid * 32 + d] * sv;
        }
    }
}

// ---------------- K6: cross fusion (wave per output row) ----------------
__global__ __launch_bounds__(256) void k6_fuse(const float* __restrict__ P,
                                               const float* __restrict__ XF,
                                               const float* __restrict__ XT,
                                               float* __restrict__ XFF,
                                               float* __restrict__ XTF) {
    int wid = blockIdx.x * 4 + (threadIdx.x >> 6);
    int lane = threadIdx.x & 63;
    if (wid < 1024) {
        int b = wid >> 6, i = wid & 63;
        const float* xf  = XF + ((size_t)b * 64 + i) * 32;
        const float* xtb = XT + (size_t)b * 4096;
        const float* w1 = P + P_W1;
        int d = lane & 31;
        float y = 0.f;
        #pragma unroll
        for (int c = 0; c < 32; c++) y = fmaf(w1[d * 32 + c], xf[c], y);
        float xtr0[32], xtr1[32];
        #pragma unroll
        for (int c = 0; c < 32; c++) {
            xtr0[c] = xtb[(size_t)lane * 32 + c];
            xtr1[c] = xtb[(size_t)(lane + 64) * 32 + c];
        }
        float s0 = 0.f, s1 = 0.f;
        #pragma unroll
        for (int c = 0; c < 32; c++) {
            float yc = __shfl(y, c, 64);
            s0 = fmaf(yc, xtr0[c], s0);
            s1 = fmaf(yc, xtr1[c], s1);
        }
        float mx = fmaxf(s0, s1);
        #pragma unroll
        for (int off = 1; off < 64; off <<= 1) mx = fmaxf(mx, __shfl_xor(mx, off, 64));
        float e0 = __expf(s0 - mx), e1 = __expf(s1 - mx);
        float sm = e0 + e1;
        #pragma unroll
        for (int off = 1; off < 64; off <<= 1) sm += __shfl_xor(sm, off, 64);
        float inv = 1.f / sm;
        float a0 = e0 * inv, a1 = e1 * inv;
        float v[32];
        #pragma unroll
        for (int c = 0; c < 32; c++) v[c] = a0 * xtr0[c] + a1 * xtr1[c];
        #pragma unroll
        for (int off = 1; off < 64; off <<= 1) {
            #pragma unroll
            for (int c = 0; c < 32; c++) v[c] += __shfl_xor(v[c], off, 64);
        }
        if (lane == 0) {
            float* o = XFF + ((size_t)b * 64 + i) * 32;
            #pragma unroll
            for (int c = 0; c < 32; c++) o[c] = xf[c] + v[c];
        }
    } else {
        int r = wid - 1024;
        int b = r >> 7, i = r & 127;
        const float* xt  = XT + ((size_t)b * 128 + i) * 32;
        const float* xfb = XF + (size_t)b * 2048;
        const float* w2 = P + P_W2;
        int d = lane & 31;
        float y = 0.f;
        #pragma unroll
        for (int c = 0; c < 32; c++) y = fmaf(w2[d * 32 + c], xt[c], y);
        float xfr[32];
        #pragma unroll
        for (int c = 0; c < 32; c++) xfr[c] = xfb[(size_t)lane * 32 + c];
        float sc0 = 0.f;
        #pragma unroll
        for (int c = 0; c < 32; c++) sc0 = fmaf(__shfl(y, c, 64), xfr[c], sc0);
        float mx = sc0;
        #pragma unroll
        for (int off = 1; off < 64; off <<= 1) mx = fmaxf(mx, __shfl_xor(mx, off, 64));
        float e = __expf(sc0 - mx);
        float sm = e;
        #pragma unroll
        for (int off = 1; off < 64; off <<= 1) sm += __shfl_xor(sm, off, 64);
        float a = e / sm;
        float v[32];
        #pragma unroll
        for (int c = 0; c < 32; c++) v[c] = a * xfr[c];
        #pragma unroll
        for (int off = 1; off < 64; off <<= 1) {
            #pragma unroll
            for (int c = 0; c < 32; c++) v[c] += __shfl_xor(v[c], off, 64);
        }
        if (lane == 0) {
            float* o = XTF + ((size_t)b * 128 + i) * 32;
            #pragma unroll
            for (int c = 0; c < 32; c++) o[c] = xt[c] + v[c];
        }
    }
}

// ---------------- K7: row-max + final FC (dtype-aware output) ----------------
__global__ __launch_bounds__(64) void k7_out(const float* __restrict__ P,
                                             const float* __restrict__ XFF,
                                             const float* __restrict__ XTF,
                                             void* __restrict__ outp) {
    __shared__ float node[64];
    int b = blockIdx.x, tid = threadIdx.x;
    if (tid < 32) {
        float m = -1e30f;
        for (int r = 0; r < 64; r++) m = fmaxf(m, XFF[((size_t)b * 64 + r) * 32 + tid]);
        node[tid] = m;
    } else {
        int c = tid - 32;
        float m = -1e30f;
        for (int r = 0; r < 128; r++) m = fmaxf(m, XTF[((size_t)b * 128 + r) * 32 + c]);
        node[tid] = m;
    }
    __syncthreads();
    if (tid < 2) {
        float z = P[P_FCB + tid];
        #pragma unroll
        for (int k = 0; k < 64; k++) z = fmaf(P[P_FCW + tid * 64 + k], node[k], z);
        int isb = (int)P[P_FLAG];
        if (isb) ((u16*)outp)[b * 2 + tid] = f2bf(z);
        else     ((float*)outp)[b * 2 + tid] = z;
    }
}

// ---------------- launch ----------------
extern "C" void kernel_launch(void* const* d_in, const int* in_sizes, int n_in,
                              void* d_out, int out_size, void* d_ws, size_t ws_size,
                              hipStream_t stream) {
    (void)in_sizes; (void)n_in; (void)out_size; (void)ws_size;
    float* W = (float*)d_ws;
    Ptrs ptrs;
    for (int i = 0; i < 39; i++) ptrs.p[i] = d_in[i];
    const void* x = d_in[0];
    float* P = W;
    u16* STC = (u16*)(W + WS_M);    // overlays M (dead after k3)
    u16* SFC = (u16*)(W + WS_XF);   // overlays XF..XFF (free until k5)

    k0_setup<<<4, 256, 0, stream>>>(ptrs, P);
    k1_conv_m<<<2048, 256, 0, stream>>>(x, P, W + WS_M);
    k2_softmax<<<128, 256, 0, stream>>>(W + WS_M, W + WS_FCATT);
    k3n<<<512, 256, 0, stream>>>(x, W + WS_M, P, W + WS_FCATT, W + WS_TCATT);
    k4a_scores<<<1536, 256, 0, stream>>>(P, W + WS_FCATT, W + WS_TCATT, SFC, STC);
    k4b_soft<<<384, 256, 0, stream>>>(P, W + WS_FCATT, W + WS_TCATT, SFC, STC,
                                      W + WS_FCGAT, W + WS_TCGAT);
    k5_pool<<<32, 256, 0, stream>>>(P, W + WS_FCGAT, W + WS_TCGAT, W + WS_XF, W + WS_XT);
    k6_fuse<<<768, 256, 0, stream>>>(P, W + WS_XF, W + WS_XT, W + WS_XFF, W + WS_XTF);
    k7_out<<<16, 64, 0, stream>>>(P, W + WS_XFF, W + WS_XTF, d_out);
}